// Round 1
// baseline (376.221 us; speedup 1.0000x reference)
//
#include <hip/hip_runtime.h>

// VQ-VAE vector quantizer, fp32-faithful baseline.
// x: [B=32, C=64, H=64, W=64] fp32, embeddings: [C=64, K=512] fp32.
// Outputs concat (float32): loss[1], quantized[B,C,H,W], perplexity[1], indices[B,H,W].

#define B_ 32
#define C_ 64
#define HW_ 4096          // H*W
#define K_ 512
#define N_ (B_ * HW_)     // 131072 positions
#define NC_ ((long long)N_ * C_)

// workspace layout (bytes):
//   0    : double sse
//   64   : int   hist[K_]
//   2112 : float enorm2[K_]

__global__ __launch_bounds__(512) void vq_init(const float* __restrict__ emb,
                                               double* __restrict__ sse,
                                               int* __restrict__ hist,
                                               float* __restrict__ enorm2) {
    int k = threadIdx.x;  // 512 threads, 1 block
    if (k == 0) *sse = 0.0;
    hist[k] = 0;
    float s = 0.f;
#pragma unroll
    for (int c = 0; c < C_; ++c) {
        float e = emb[c * K_ + k];
        s += e * e;
    }
    enorm2[k] = s;
}

__global__ __launch_bounds__(256) void vq_main(const float* __restrict__ x,
                                               const float* __restrict__ emb,
                                               const float* __restrict__ enorm2,
                                               float* __restrict__ out_q,
                                               float* __restrict__ out_idx,
                                               double* __restrict__ sse,
                                               int* __restrict__ hist) {
    int n  = blockIdx.x * 256 + threadIdx.x;   // position id
    int b  = n >> 12;                          // / 4096
    int hw = n & 4095;
    const float* xp = x + (size_t)b * C_ * HW_ + hw;

    // Load z into registers (coalesced across lanes per channel), compute ||z||^2.
    float z[C_];
    float zn = 0.f;
#pragma unroll
    for (int c = 0; c < C_; ++c) {
        z[c] = xp[(size_t)c * HW_];
        zn += z[c] * z[c];
    }

    // Argmin over K codes; k-unroll x4 for 4 independent FMA chains.
    // emb/enorm2 indices are wave-uniform -> compiler emits s_load, FMA takes SGPR operand.
    float best = 3.4e38f;
    int   bi   = 0;
    for (int k0 = 0; k0 < K_; k0 += 4) {
        float d0 = 0.f, d1 = 0.f, d2 = 0.f, d3 = 0.f;
#pragma unroll
        for (int c = 0; c < C_; ++c) {
            const float zc = z[c];
            const float* ep = emb + c * K_ + k0;
            d0 += zc * ep[0];
            d1 += zc * ep[1];
            d2 += zc * ep[2];
            d3 += zc * ep[3];
        }
        // dist = (zn + en) - 2*dot  (matches reference evaluation order)
        float t0 = (zn + enorm2[k0 + 0]) - 2.f * d0;
        float t1 = (zn + enorm2[k0 + 1]) - 2.f * d1;
        float t2 = (zn + enorm2[k0 + 2]) - 2.f * d2;
        float t3 = (zn + enorm2[k0 + 3]) - 2.f * d3;
        if (t0 < best) { best = t0; bi = k0 + 0; }
        if (t1 < best) { best = t1; bi = k0 + 1; }
        if (t2 < best) { best = t2; bi = k0 + 2; }
        if (t3 < best) { best = t3; bi = k0 + 3; }
    }

    out_idx[n] = (float)bi;
    atomicAdd(&hist[bi], 1);

    // Gather chosen code, write quantized output (numerically == straight-through),
    // and accumulate squared error.
    const float* ep = emb + bi;
    float* qp = out_q + (size_t)b * C_ * HW_ + hw;
    float sacc = 0.f;
#pragma unroll
    for (int c = 0; c < C_; ++c) {
        float q = ep[c * K_];
        qp[(size_t)c * HW_] = q;
        float d = q - z[c];
        sacc += d * d;
    }

    // Wave-level reduce (wave64), one double atomic per wave.
#pragma unroll
    for (int off = 32; off > 0; off >>= 1)
        sacc += __shfl_down(sacc, off, 64);
    if ((threadIdx.x & 63) == 0)
        atomicAdd(sse, (double)sacc);
}

__global__ __launch_bounds__(512) void vq_final(const int* __restrict__ hist,
                                                const double* __restrict__ sse,
                                                float* __restrict__ out_loss,
                                                float* __restrict__ out_perp) {
    __shared__ float wsum[8];
    int k = threadIdx.x;  // 512 threads, 1 block
    float p = (float)hist[k] / (float)N_;
    float t = p * logf(p + 1e-10f);
#pragma unroll
    for (int off = 32; off > 0; off >>= 1)
        t += __shfl_down(t, off, 64);
    if ((k & 63) == 0) wsum[k >> 6] = t;
    __syncthreads();
    if (k == 0) {
        float s = 0.f;
#pragma unroll
        for (int w = 0; w < 8; ++w) s += wsum[w];
        *out_perp = expf(-s);
        *out_loss = (float)(1.25 * (*sse) / (double)NC_);
    }
}

extern "C" void kernel_launch(void* const* d_in, const int* in_sizes, int n_in,
                              void* d_out, int out_size, void* d_ws, size_t ws_size,
                              hipStream_t stream) {
    const float* x   = (const float*)d_in[0];
    const float* emb = (const float*)d_in[1];

    float* out        = (float*)d_out;
    float* out_loss   = out;                       // [0]
    float* out_q      = out + 1;                   // [1 .. 1+8388608)
    float* out_perp   = out + 1 + (size_t)N_ * C_; // [8388609]
    float* out_idx    = out + 2 + (size_t)N_ * C_; // [8388610 ..)

    char* ws = (char*)d_ws;
    double* sse   = (double*)(ws + 0);
    int*   hist   = (int*)(ws + 64);
    float* enorm2 = (float*)(ws + 2112);

    vq_init<<<1, 512, 0, stream>>>(emb, sse, hist, enorm2);
    vq_main<<<N_ / 256, 256, 0, stream>>>(x, emb, enorm2, out_q, out_idx, sse, hist);
    vq_final<<<1, 512, 0, stream>>>(hist, sse, out_loss, out_perp);
}

// Round 3
// 309.665 us; speedup vs baseline: 1.2149x; 1.2149x over previous
//
#include <hip/hip_runtime.h>

// VQ-VAE vector quantizer — bf16x3 split-GEMM on MFMA + provably-sound exact
// fp32 rescue for rows whose top-2 approx distance gap is below the error bound.
// x: [B=32, C=64, H=64, W=64] fp32, embeddings: [C=64, K=512] fp32.
// Outputs concat (float32): loss[1], quantized[B,C,H,W], perplexity[1], indices[B,H,W].

#define B_ 32
#define C_ 64
#define HW_ 4096
#define K_ 512
#define N_ (B_ * HW_)
#define NC_ ((long long)N_ * C_)
#define ROWS_ 128            // rows (positions) per block

typedef __attribute__((ext_vector_type(8))) short short8;
typedef __attribute__((ext_vector_type(4))) float float4_t;

// ---- workspace layout (bytes) ----
// 0       double sse
// 56      float snmax                  max_k ||-2*e_k||^2
// 64      int   hist[512]
// 2112    float en[512]                ||e_k||^2 (sequential-c sum, ref-order)
// 4160    float embT32[512*64]         exact fp32 emb, [code][c]
// 135232  ushort embT_hi[512*64]       bf16 hi of (-2*e), [code][c]
// 200768  ushort embT_lo[512*64]       bf16 lo of (-2*e)

__device__ __forceinline__ unsigned short f2bf(float f) {
    unsigned u = __float_as_uint(f);
    u += 0x7fffu + ((u >> 16) & 1u);   // RNE
    return (unsigned short)(u >> 16);
}
__device__ __forceinline__ float bf2f(unsigned short h) {
    return __uint_as_float(((unsigned)h) << 16);
}

// LDS A-tile (bf16 frag) offset: [row-tile][k-group][row-in-tile][8 contiguous k]
__device__ __forceinline__ int offA(int r, int c) {
    return ((r >> 4) << 10) + ((c >> 3) << 7) + ((r & 15) << 3) + (c & 7);
}

// merge two (min, argmin, secondmin) triples (indices only tracked for min)
__device__ __forceinline__ void merge2(float& m1, int& i1, float& m2,
                                       float om1, int oi1, float om2) {
    if (om1 < m1) { m2 = fminf(m1, om2); m1 = om1; i1 = oi1; }
    else          { m2 = fminf(m2, om1); }
}

// ---------------- prologue ----------------
__global__ __launch_bounds__(512) void vq_init(const float* __restrict__ emb,
                                               double* __restrict__ sse,
                                               float* __restrict__ snmax_p,
                                               int* __restrict__ hist,
                                               float* __restrict__ en,
                                               float* __restrict__ embT32,
                                               unsigned short* __restrict__ embT_hi,
                                               unsigned short* __restrict__ embT_lo) {
    __shared__ float smax[8];
    int k = threadIdx.x;                  // 0..511
    if (blockIdx.x < 64) {
        int c = blockIdx.x;
        float e = emb[c * K_ + k];        // coalesced over k
        embT32[k * C_ + c] = e;
        float s = -2.0f * e;
        unsigned short hi = f2bf(s);
        unsigned short lo = f2bf(s - bf2f(hi));
        embT_hi[k * C_ + c] = hi;
        embT_lo[k * C_ + c] = lo;
    } else {
        if (k == 0) *sse = 0.0;
        hist[k] = 0;
        float s = 0.f;
#pragma unroll
        for (int c = 0; c < C_; ++c) {
            float e = emb[c * K_ + k];
            s += e * e;                   // sequential c, same order as ref-passing R1
        }
        en[k] = s;
        // snmax = 4 * max_k ||e_k||^2
        float m = s;
#pragma unroll
        for (int off = 32; off > 0; off >>= 1)
            m = fmaxf(m, __shfl_down(m, off, 64));
        if ((k & 63) == 0) smax[k >> 6] = m;
        __syncthreads();
        if (k == 0) {
            float mm = smax[0];
#pragma unroll
            for (int w = 1; w < 8; ++w) mm = fmaxf(mm, smax[w]);
            *snmax_p = 4.0f * mm;
        }
    }
}

// ---------------- main kernel ----------------
__global__ __launch_bounds__(256, 2) void vq_main(const float* __restrict__ x,
                                                  const float* __restrict__ en,
                                                  const float* __restrict__ embT32,
                                                  const unsigned short* __restrict__ embT_hi,
                                                  const unsigned short* __restrict__ embT_lo,
                                                  const float* __restrict__ snmax_p,
                                                  float* __restrict__ out_q,
                                                  float* __restrict__ out_idx,
                                                  double* __restrict__ sse,
                                                  int* __restrict__ hist) {
    __shared__ float A32[ROWS_ * 65];            // exact fp32 z, padded ld=65 (33.3 KB)
    __shared__ unsigned short Ahi[ROWS_ * C_];   // 16 KB, MFMA frag order
    __shared__ unsigned short Alo[ROWS_ * C_];   // 16 KB
    __shared__ float znp[2 * ROWS_];             // zn partials -> zn[r] in znp[r]
    __shared__ float redv[ROWS_ * 4];            // per-row per-wave min
    __shared__ float redv2[ROWS_ * 4];           // per-row per-wave second-min
    __shared__ int   redi[ROWS_ * 4];            // per-row per-wave argmin
    __shared__ int   biarr[ROWS_];
    __shared__ int   flaglist[ROWS_];
    __shared__ int   nflag;

    const int t   = threadIdx.x;
    const int n0  = blockIdx.x * ROWS_;
    const int b   = n0 >> 12;
    const int hw0 = n0 & 4095;
    const float* xbase = x + ((size_t)b << 18) + hw0;

    if (t == 0) nflag = 0;

    // ---- stage z: exact fp32 + bf16 hi/lo (frag order); zn partials ----
    // thread t owns row r=t&127, channels c = 2*i + (t>>7)
    float znacc = 0.f;
#pragma unroll 4
    for (int i = 0; i < 32; ++i) {
        int id = (i << 8) + t;
        int c = id >> 7;
        int r = id & 127;
        float v = xbase[((size_t)c << 12) + r];   // coalesced in r
        A32[r * 65 + c] = v;
        znacc += v * v;
        unsigned short hi = f2bf(v);
        unsigned short lo = f2bf(v - bf2f(hi));
        int o = offA(r, c);
        Ahi[o] = hi;
        Alo[o] = lo;
    }
    znp[((t >> 7) << 7) + (t & 127)] = znacc;
    __syncthreads();

    // ---- MFMA distance GEMM + per-row top-2 tracking ----
    const int lane = t & 63;
    const int w    = t >> 6;             // wave id 0..3: codes [w*128, w*128+128)
    const int ln15 = lane & 15;
    const int quad = lane >> 4;
    const int colbase = w << 7;

    short8 bh[8][2], bl[8][2];
    float  enr[8];
#pragma unroll
    for (int ct = 0; ct < 8; ++ct) {
        int bcol = colbase + (ct << 4) + ln15;
        int be = bcol * C_ + (quad << 3);
        bh[ct][0] = *(const short8*)(embT_hi + be);
        bh[ct][1] = *(const short8*)(embT_hi + be + 32);
        bl[ct][0] = *(const short8*)(embT_lo + be);
        bl[ct][1] = *(const short8*)(embT_lo + be + 32);
        enr[ct] = en[bcol];
    }

    for (int rt = 0; rt < 8; ++rt) {
        const int ab = (rt << 10) + (quad << 7) + (ln15 << 3);
        short8 ah0 = *(const short8*)(Ahi + ab);
        short8 ah1 = *(const short8*)(Ahi + ab + (4 << 7));
        short8 al0 = *(const short8*)(Alo + ab);
        short8 al1 = *(const short8*)(Alo + ab + (4 << 7));

        float4_t acc[8];
#pragma unroll
        for (int ct = 0; ct < 8; ++ct) {
            float4_t a = {0.f, 0.f, 0.f, 0.f};
            a = __builtin_amdgcn_mfma_f32_16x16x32_bf16(ah0, bh[ct][0], a, 0, 0, 0);
            a = __builtin_amdgcn_mfma_f32_16x16x32_bf16(ah1, bh[ct][1], a, 0, 0, 0);
            a = __builtin_amdgcn_mfma_f32_16x16x32_bf16(ah0, bl[ct][0], a, 0, 0, 0);
            a = __builtin_amdgcn_mfma_f32_16x16x32_bf16(ah1, bl[ct][1], a, 0, 0, 0);
            a = __builtin_amdgcn_mfma_f32_16x16x32_bf16(al0, bh[ct][0], a, 0, 0, 0);
            a = __builtin_amdgcn_mfma_f32_16x16x32_bf16(al1, bh[ct][1], a, 0, 0, 0);
            acc[ct] = a;
        }

        // D layout: col = lane&15 (code), row = quad*4 + reg (position)
#pragma unroll
        for (int reg = 0; reg < 4; ++reg) {
            float m1 = 3.4e38f, m2 = 3.4e38f;
            int   i1 = 0;
#pragma unroll
            for (int ct = 0; ct < 8; ++ct) {
                float v = acc[ct][reg] + enr[ct];
                int idx = colbase + (ct << 4) + ln15;
                if (v < m1) { m2 = m1; m1 = v; i1 = idx; }
                else        { m2 = fminf(m2, v); }
            }
            // 16-lane butterfly (codes spread over ln15)
#pragma unroll
            for (int s = 1; s < 16; s <<= 1) {
                float om1 = __shfl_xor(m1, s, 16);
                int   oi1 = __shfl_xor(i1, s, 16);
                float om2 = __shfl_xor(m2, s, 16);
                merge2(m1, i1, m2, om1, oi1, om2);
            }
            if (ln15 == 0) {
                int row = (rt << 4) + (quad << 2) + reg;
                redv [row * 4 + w] = m1;
                redi [row * 4 + w] = i1;
                redv2[row * 4 + w] = m2;
            }
        }
    }
    __syncthreads();

    // ---- cross-wave combine + flag decision ----
    const float snm = *snmax_p;
    if (t < ROWS_) {
        float m1 = redv[t * 4], m2 = redv2[t * 4];
        int   i1 = redi[t * 4];
#pragma unroll
        for (int e = 1; e < 4; ++e)
            merge2(m1, i1, m2, redv[t * 4 + e], redi[t * 4 + e], redv2[t * 4 + e]);
        float znr = znp[t] + znp[128 + t];
        znp[t] = znr;                     // zn[r] for rescue
        // sound |approx - exact| bound: split truncation (3*2^-16) + fp32 sum slack
        float W = 1.4e-4f * __builtin_sqrtf(znr * snm) + 1e-3f;   // = 2*eps
        biarr[t] = i1;
        if (m2 > m1 + W) {
            out_idx[n0 + t] = (float)i1;
            atomicAdd(&hist[i1], 1);
        } else {
            int p = atomicAdd(&nflag, 1);
            flaglist[p] = t;
        }
    }
    __syncthreads();

    // ---- exact fp32 rescue for flagged rows (one wave per row) ----
    int nf = nflag;
    for (int f = w; f < nf; f += 4) {
        int r = flaglist[f];
        float znr = znp[r];
        float d[8];
#pragma unroll
        for (int j = 0; j < 8; ++j) d[j] = 0.f;
        const float4* ez = (const float4*)embT32;   // [k][c/4]
        for (int c4 = 0; c4 < 16; ++c4) {
            float z0 = A32[r * 65 + c4 * 4 + 0];    // broadcast reads
            float z1 = A32[r * 65 + c4 * 4 + 1];
            float z2 = A32[r * 65 + c4 * 4 + 2];
            float z3 = A32[r * 65 + c4 * 4 + 3];
#pragma unroll
            for (int j = 0; j < 8; ++j) {
                float4 e = ez[(lane * 8 + j) * 16 + c4];
                d[j] = fmaf(z0, e.x, d[j]);
                d[j] = fmaf(z1, e.y, d[j]);
                d[j] = fmaf(z2, e.z, d[j]);
                d[j] = fmaf(z3, e.w, d[j]);
            }
        }
        float best = 3.4e38f;
        int   bidx = 0;
#pragma unroll
        for (int j = 0; j < 8; ++j) {
            int k = lane * 8 + j;
            float dist = (znr + en[k]) - 2.f * d[j];   // reference eval order
            if (dist < best) { best = dist; bidx = k; }
        }
#pragma unroll
        for (int off = 32; off > 0; off >>= 1) {
            float ov = __shfl_down(best, off, 64);
            int   oi = __shfl_down(bidx, off, 64);
            if (ov < best || (ov == best && oi < bidx)) { best = ov; bidx = oi; }
        }
        if (lane == 0) {
            biarr[r] = bidx;
            out_idx[n0 + r] = (float)bidx;
            atomicAdd(&hist[bidx], 1);
        }
    }
    __syncthreads();

    // ---- phase 2: gather exact codes, write q, accumulate SSE ----
    float* qbase = out_q + ((size_t)b << 18) + hw0;
    float sacc = 0.f;
#pragma unroll 4
    for (int i = 0; i < 32; ++i) {
        int id = (i << 8) + t;
        int c = id >> 7;
        int r = id & 127;
        int bi2 = biarr[r];
        float q = embT32[bi2 * C_ + c];
        float z = A32[r * 65 + c];               // exact fp32 z
        float dd = q - z;
        sacc += dd * dd;
        qbase[((size_t)c << 12) + r] = q;        // coalesced in r
    }
#pragma unroll
    for (int off = 32; off > 0; off >>= 1)
        sacc += __shfl_down(sacc, off, 64);
    if (lane == 0)
        atomicAdd(sse, (double)sacc);
}

// ---------------- epilogue: loss + perplexity ----------------
__global__ __launch_bounds__(512) void vq_final(const int* __restrict__ hist,
                                                const double* __restrict__ sse,
                                                float* __restrict__ out_loss,
                                                float* __restrict__ out_perp) {
    __shared__ float wsum[8];
    int k = threadIdx.x;
    float p = (float)hist[k] / (float)N_;
    float t = p * logf(p + 1e-10f);
#pragma unroll
    for (int off = 32; off > 0; off >>= 1)
        t += __shfl_down(t, off, 64);
    if ((k & 63) == 0) wsum[k >> 6] = t;
    __syncthreads();
    if (k == 0) {
        float s = 0.f;
#pragma unroll
        for (int w = 0; w < 8; ++w) s += wsum[w];
        *out_perp = expf(-s);
        *out_loss = (float)(1.25 * (*sse) / (double)NC_);
    }
}

extern "C" void kernel_launch(void* const* d_in, const int* in_sizes, int n_in,
                              void* d_out, int out_size, void* d_ws, size_t ws_size,
                              hipStream_t stream) {
    const float* x   = (const float*)d_in[0];
    const float* emb = (const float*)d_in[1];

    float* out      = (float*)d_out;
    float* out_loss = out;
    float* out_q    = out + 1;
    float* out_perp = out + 1 + (size_t)N_ * C_;
    float* out_idx  = out + 2 + (size_t)N_ * C_;

    char* ws = (char*)d_ws;
    double*         sse     = (double*)(ws + 0);
    float*          snmax_p = (float*)(ws + 56);
    int*            hist    = (int*)(ws + 64);
    float*          en      = (float*)(ws + 2112);
    float*          embT32  = (float*)(ws + 4160);
    unsigned short* embT_hi = (unsigned short*)(ws + 135232);
    unsigned short* embT_lo = (unsigned short*)(ws + 200768);

    vq_init<<<65, 512, 0, stream>>>(emb, sse, snmax_p, hist, en, embT32, embT_hi, embT_lo);
    vq_main<<<N_ / ROWS_, 256, 0, stream>>>(x, en, embT32, embT_hi, embT_lo, snmax_p,
                                            out_q, out_idx, sse, hist);
    vq_final<<<1, 512, 0, stream>>>(hist, sse, out_loss, out_perp);
}

// Round 4
// 268.614 us; speedup vs baseline: 1.4006x; 1.1528x over previous
//
#include <hip/hip_runtime.h>

// VQ-VAE vector quantizer — R4.
// Structure: bf16x3 split-GEMM on MFMA + sound exact-fp32 rescue (R3, passed),
// restructured to fix R3's spill (128 VGPRs of resident B-frags -> 74 MB scratch
// writes) and occupancy (73 KB LDS -> 2 blocks/CU, 14% occ).
//  - waves split ROWS (2 row-tiles each, A-frags resident = 32 VGPRs),
//    codes streamed in 16 passes x 16-code col-tiles (B-frags 16 VGPRs live).
//  - no fp32 z tile in LDS: SSE from z_rec=hi+lo (err ~2^-24 rel, loss err ~1e-6);
//    rescue re-reads exact x from global (L2-hot, ~1% of rows).
//  - B-frags pre-swizzled to fragment-linear layout: each load = 1 KB contiguous.
//  - loss/perplexity fused via device-scope done counter (one launch saved).

#define B_ 32
#define C_ 64
#define HW_ 4096
#define K_ 512
#define N_ (B_ * HW_)
#define NC_ ((long long)N_ * C_)
#define ROWS_ 128

typedef __attribute__((ext_vector_type(8))) short short8;
typedef __attribute__((ext_vector_type(4))) float float4_t;

// ---- workspace layout (bytes) ----
// 0       double sse
// 8       int    done
// 56      float  snmax               4*max_k ||e_k||^2
// 64      int    hist[512]
// 2112    float  en[512]             ||e_k||^2
// 4160    float  embT32[512*64]      exact fp32 emb, [code][c]
// 135232  ushort fBhi[512*64]        bf16 hi of (-2e), fragment-linear
// 200768  ushort fBlo[512*64]        bf16 lo of (-2e), fragment-linear

__device__ __forceinline__ unsigned short f2bf(float f) {
    unsigned u = __float_as_uint(f);
    u += 0x7fffu + ((u >> 16) & 1u);   // RNE
    return (unsigned short)(u >> 16);
}
__device__ __forceinline__ float bf2f(unsigned short h) {
    return __uint_as_float(((unsigned)h) << 16);
}
// LDS A-tile (bf16 frag) offset: [row-tile][k-group][row-in-tile][8 k]
__device__ __forceinline__ int offA(int r, int c) {
    return ((r >> 4) << 10) + ((c >> 3) << 7) + ((r & 15) << 3) + (c & 7);
}
__device__ __forceinline__ void merge2(float& m1, int& i1, float& m2,
                                       float om1, int oi1, float om2) {
    if (om1 < m1) { m2 = fminf(m1, om2); m1 = om1; i1 = oi1; }
    else          { m2 = fminf(m2, om1); }
}

// ---------------- prologue ----------------
__global__ __launch_bounds__(512) void vq_init(const float* __restrict__ emb,
                                               double* __restrict__ sse,
                                               int* __restrict__ done,
                                               float* __restrict__ snmax_p,
                                               int* __restrict__ hist,
                                               float* __restrict__ en,
                                               float* __restrict__ embT32,
                                               unsigned short* __restrict__ fBhi,
                                               unsigned short* __restrict__ fBlo) {
    __shared__ float smax[8];
    int k = threadIdx.x;                  // code 0..511
    if (blockIdx.x < 64) {
        int c = blockIdx.x;
        float e = emb[c * K_ + k];        // coalesced over k
        embT32[k * C_ + c] = e;
        float s = -2.0f * e;
        unsigned short hi = f2bf(s);
        unsigned short lo = f2bf(s - bf2f(hi));
        // fragment-linear: pass=k>>5, ct=(k>>4)&1, kk=c>>5, lane=((c&31)>>3)<<4 | (k&15)
        int kk   = c >> 5;
        int lane = (((c & 31) >> 3) << 4) + (k & 15);
        int fb   = ((k >> 5) << 2) + (((k >> 4) & 1) << 1) + kk;
        int off  = (fb << 9) + (lane << 3) + (c & 7);
        fBhi[off] = hi;
        fBlo[off] = lo;
    } else {
        if (k == 0) { *sse = 0.0; *done = 0; }
        hist[k] = 0;
        float s = 0.f;
#pragma unroll
        for (int c = 0; c < C_; ++c) {
            float e = emb[c * K_ + k];
            s += e * e;
        }
        en[k] = s;
        float m = s;
#pragma unroll
        for (int off = 32; off > 0; off >>= 1)
            m = fmaxf(m, __shfl_down(m, off, 64));
        if ((k & 63) == 0) smax[k >> 6] = m;
        __syncthreads();
        if (k == 0) {
            float mm = smax[0];
#pragma unroll
            for (int w2 = 1; w2 < 8; ++w2) mm = fmaxf(mm, smax[w2]);
            *snmax_p = 4.0f * mm;
        }
    }
}

// ---------------- main kernel (fused final) ----------------
__global__ __launch_bounds__(256, 3) void vq_main(const float* __restrict__ x,
                                                  const float* __restrict__ en_g,
                                                  const float* __restrict__ embT32,
                                                  const unsigned short* __restrict__ fBhi,
                                                  const unsigned short* __restrict__ fBlo,
                                                  const float* __restrict__ snmax_p,
                                                  float* __restrict__ out_q,
                                                  float* __restrict__ out_idx,
                                                  float* __restrict__ out_loss,
                                                  float* __restrict__ out_perp,
                                                  double* __restrict__ sse_g,
                                                  int* __restrict__ hist,
                                                  int* __restrict__ done) {
    __shared__ unsigned short Ahi[ROWS_ * C_];   // 16 KB, frag order
    __shared__ unsigned short Alo[ROWS_ * C_];   // 16 KB
    __shared__ float znp[2 * ROWS_];
    __shared__ float sEn[K_];
    __shared__ int   biarr[ROWS_];
    __shared__ int   flaglist[ROWS_];
    __shared__ int   nflag;
    __shared__ int   islast;

    const int t   = threadIdx.x;
    const int n0  = blockIdx.x * ROWS_;
    const int b   = n0 >> 12;
    const int hw0 = n0 & 4095;
    const float* xbase = x + ((size_t)b << 18) + hw0;

    if (t == 0) nflag = 0;
    sEn[t]       = en_g[t];
    sEn[256 + t] = en_g[256 + t];

    // ---- stage z: bf16 hi/lo (frag order) + zn partials ----
    // thread owns row r = t&127, c = 2i + (t>>7)
    float znacc = 0.f;
#pragma unroll 8
    for (int i = 0; i < 32; ++i) {
        int id = (i << 8) + t;
        int c = id >> 7;
        int r = id & 127;
        float v = xbase[((size_t)c << 12) + r];   // 256B coalesced
        znacc += v * v;
        unsigned short hi = f2bf(v);
        unsigned short lo = f2bf(v - bf2f(hi));
        int o = offA(r, c);
        Ahi[o] = hi;
        Alo[o] = lo;
    }
    znp[((t >> 7) << 7) + (t & 127)] = znacc;
    __syncthreads();

    const int lane = t & 63;
    const int w    = t >> 6;             // wave owns row-tiles {2w, 2w+1}
    const int ln15 = lane & 15;
    const int quad = lane >> 4;
    const float snm = *snmax_p;

    // ---- A-frags resident (32 VGPRs) ----
    short8 ah[2][2], al[2][2];
#pragma unroll
    for (int rtl = 0; rtl < 2; ++rtl) {
        int ab = (((2 * w) + rtl) << 10) + (quad << 7) + (ln15 << 3);
        ah[rtl][0] = *(const short8*)(Ahi + ab);
        ah[rtl][1] = *(const short8*)(Ahi + ab + 512);
        al[rtl][0] = *(const short8*)(Alo + ab);
        al[rtl][1] = *(const short8*)(Alo + ab + 512);
    }

    // ---- stream all 512 codes: 16 passes x 2 col-tiles; track per-row top-2 ----
    float m1[2][4], m2[2][4];
    int   i1[2][4];
#pragma unroll
    for (int rtl = 0; rtl < 2; ++rtl)
#pragma unroll
        for (int reg = 0; reg < 4; ++reg) {
            m1[rtl][reg] = 3.4e38f; m2[rtl][reg] = 3.4e38f; i1[rtl][reg] = 0;
        }

    for (int p = 0; p < 16; ++p) {
#pragma unroll
        for (int ct = 0; ct < 2; ++ct) {
            const unsigned short* fh = fBhi + ((((p << 2) + (ct << 1)) << 9) + (lane << 3));
            const unsigned short* fl = fBlo + ((((p << 2) + (ct << 1)) << 9) + (lane << 3));
            short8 bh0 = *(const short8*)(fh);          // 1 KB contiguous per instr
            short8 bh1 = *(const short8*)(fh + 512);
            short8 bl0 = *(const short8*)(fl);
            short8 bl1 = *(const short8*)(fl + 512);
            float env = sEn[(p << 5) + (ct << 4) + ln15];
            int   idx = (p << 5) + (ct << 4) + ln15;
#pragma unroll
            for (int rtl = 0; rtl < 2; ++rtl) {
                float4_t a = {0.f, 0.f, 0.f, 0.f};
                a = __builtin_amdgcn_mfma_f32_16x16x32_bf16(ah[rtl][0], bh0, a, 0, 0, 0);
                a = __builtin_amdgcn_mfma_f32_16x16x32_bf16(ah[rtl][1], bh1, a, 0, 0, 0);
                a = __builtin_amdgcn_mfma_f32_16x16x32_bf16(ah[rtl][0], bl0, a, 0, 0, 0);
                a = __builtin_amdgcn_mfma_f32_16x16x32_bf16(ah[rtl][1], bl1, a, 0, 0, 0);
                a = __builtin_amdgcn_mfma_f32_16x16x32_bf16(al[rtl][0], bh0, a, 0, 0, 0);
                a = __builtin_amdgcn_mfma_f32_16x16x32_bf16(al[rtl][1], bh1, a, 0, 0, 0);
#pragma unroll
                for (int reg = 0; reg < 4; ++reg) {
                    float v = a[reg] + env;
                    if (v < m1[rtl][reg]) {
                        m2[rtl][reg] = m1[rtl][reg]; m1[rtl][reg] = v; i1[rtl][reg] = idx;
                    } else {
                        m2[rtl][reg] = fminf(m2[rtl][reg], v);
                    }
                }
            }
        }
    }

    // ---- 16-lane butterfly finalize + flag decision (no cross-wave reduce) ----
#pragma unroll
    for (int rtl = 0; rtl < 2; ++rtl)
#pragma unroll
        for (int reg = 0; reg < 4; ++reg) {
            float a1 = m1[rtl][reg], a2 = m2[rtl][reg];
            int   ai = i1[rtl][reg];
#pragma unroll
            for (int s = 1; s < 16; s <<= 1) {
                float o1 = __shfl_xor(a1, s, 16);
                int   oi = __shfl_xor(ai, s, 16);
                float o2 = __shfl_xor(a2, s, 16);
                merge2(a1, ai, a2, o1, oi, o2);
            }
            if (ln15 == 0) {
                int row = (((2 * w) + rtl) << 4) + (quad << 2) + reg;
                float znr = znp[row] + znp[128 + row];
                float W = 1.4e-4f * __builtin_sqrtf(znr * snm) + 1e-3f;  // sound err bound x2
                biarr[row] = ai;
                if (a2 > a1 + W) {          // gap > W  =>  approx argmin == exact argmin
                    out_idx[n0 + row] = (float)ai;
                    atomicAdd(&hist[ai], 1);
                } else {
                    int pos = atomicAdd(&nflag, 1);
                    flaglist[pos] = row;
                }
            }
        }
    __syncthreads();

    // ---- exact fp32 rescue (one wave per flagged row; ~1% of rows) ----
    int nf = nflag;
    for (int f = w; f < nf; f += 4) {
        int r = flaglist[f];
        float zl = xbase[((size_t)lane << 12) + r];   // exact z[lane], L2-hot
        float d[8];
#pragma unroll
        for (int j = 0; j < 8; ++j) d[j] = 0.f;
        for (int c4 = 0; c4 < 16; ++c4) {
            float z0 = __shfl(zl, (c4 << 2) + 0, 64);
            float z1 = __shfl(zl, (c4 << 2) + 1, 64);
            float z2 = __shfl(zl, (c4 << 2) + 2, 64);
            float z3 = __shfl(zl, (c4 << 2) + 3, 64);
#pragma unroll
            for (int j = 0; j < 8; ++j) {
                float4 e = *(const float4*)(embT32 + ((((lane << 3) + j) << 6) + (c4 << 2)));
                d[j] = fmaf(z0, e.x, d[j]);
                d[j] = fmaf(z1, e.y, d[j]);
                d[j] = fmaf(z2, e.z, d[j]);
                d[j] = fmaf(z3, e.w, d[j]);
            }
        }
        float znr = znp[r] + znp[128 + r];   // zn is a uniform row shift: argmin-safe
        float best = 3.4e38f;
        int   bidx = 0;
#pragma unroll
        for (int j = 0; j < 8; ++j) {
            int k = (lane << 3) + j;
            float dist = (znr + sEn[k]) - 2.f * d[j];   // reference eval order
            if (dist < best) { best = dist; bidx = k; }
        }
#pragma unroll
        for (int off = 32; off > 0; off >>= 1) {
            float ov = __shfl_down(best, off, 64);
            int   oi = __shfl_down(bidx, off, 64);
            if (ov < best || (ov == best && oi < bidx)) { best = ov; bidx = oi; }
        }
        if (lane == 0) {
            biarr[r] = bidx;
            out_idx[n0 + r] = (float)bidx;
            atomicAdd(&hist[bidx], 1);
        }
    }
    __syncthreads();

    // ---- phase 2: float4 gather of chosen codes, coalesced q store, SSE ----
    float sacc = 0.f;
#pragma unroll
    for (int i = 0; i < 2; ++i) {
        int id2 = (i << 8) + t;           // (r, 16-col chunk p2)
        int r  = id2 & 127;
        int p2 = id2 >> 7;                // 0..3
        int code = biarr[r];
        const float* ebase = embT32 + ((code << 6) + (p2 << 4));
        float* qb = out_q + ((size_t)b << 18) + hw0 + r;
#pragma unroll
        for (int j = 0; j < 4; ++j) {
            float4 q4 = *(const float4*)(ebase + (j << 2));   // 16B gather, L2-hot
            int c = (p2 << 4) + (j << 2);
            int o = offA(r, c);
            ushort4 h4 = *(const ushort4*)(Ahi + o);
            ushort4 l4 = *(const ushort4*)(Alo + o);
            float z0 = bf2f(h4.x) + bf2f(l4.x);
            float z1 = bf2f(h4.y) + bf2f(l4.y);
            float z2 = bf2f(h4.z) + bf2f(l4.z);
            float z3 = bf2f(h4.w) + bf2f(l4.w);
            float d0 = q4.x - z0, d1 = q4.y - z1, d2 = q4.z - z2, d3 = q4.w - z3;
            sacc += d0 * d0 + d1 * d1 + d2 * d2 + d3 * d3;
            qb[(size_t)(c + 0) << 12] = q4.x;   // 256B coalesced per instr
            qb[(size_t)(c + 1) << 12] = q4.y;
            qb[(size_t)(c + 2) << 12] = q4.z;
            qb[(size_t)(c + 3) << 12] = q4.w;
        }
    }
#pragma unroll
    for (int off = 32; off > 0; off >>= 1)
        sacc += __shfl_down(sacc, off, 64);
    if (lane == 0)
        atomicAdd(sse_g, (double)sacc);

    // ---- fused epilogue: last block computes loss + perplexity ----
    if (t == 0) {
        __threadfence();
        islast = (atomicAdd(done, 1) == (N_ / ROWS_) - 1);
    }
    __syncthreads();
    if (islast && t < 64) {
        float s = 0.f;
#pragma unroll
        for (int j = 0; j < 8; ++j) {
            int h = atomicAdd(&hist[(t << 3) + j], 0);   // device-coherent read
            float pp = (float)h / (float)N_;
            s += pp * logf(pp + 1e-10f);
        }
#pragma unroll
        for (int off = 32; off > 0; off >>= 1)
            s += __shfl_down(s, off, 64);
        if (t == 0) {
            double sv = atomicAdd(sse_g, 0.0);
            out_loss[0] = (float)(1.25 * sv / (double)NC_);
            out_perp[0] = expf(-s);
        }
    }
}

extern "C" void kernel_launch(void* const* d_in, const int* in_sizes, int n_in,
                              void* d_out, int out_size, void* d_ws, size_t ws_size,
                              hipStream_t stream) {
    const float* x   = (const float*)d_in[0];
    const float* emb = (const float*)d_in[1];

    float* out      = (float*)d_out;
    float* out_loss = out;
    float* out_q    = out + 1;
    float* out_perp = out + 1 + (size_t)N_ * C_;
    float* out_idx  = out + 2 + (size_t)N_ * C_;

    char* ws = (char*)d_ws;
    double*         sse     = (double*)(ws + 0);
    int*            done    = (int*)(ws + 8);
    float*          snmax_p = (float*)(ws + 56);
    int*            hist    = (int*)(ws + 64);
    float*          en      = (float*)(ws + 2112);
    float*          embT32  = (float*)(ws + 4160);
    unsigned short* fBhi    = (unsigned short*)(ws + 135232);
    unsigned short* fBlo    = (unsigned short*)(ws + 200768);

    vq_init<<<65, 512, 0, stream>>>(emb, sse, done, snmax_p, hist, en, embT32, fBhi, fBlo);
    vq_main<<<N_ / ROWS_, 256, 0, stream>>>(x, en, embT32, fBhi, fBlo, snmax_p,
                                            out_q, out_idx, out_loss, out_perp,
                                            sse, hist, done);
}

// Round 5
// 161.231 us; speedup vs baseline: 2.3334x; 1.6660x over previous
//
#include <hip/hip_runtime.h>

// VQ-VAE vector quantizer — R5.
// R4 structure (bf16x3 split-GEMM on MFMA + sound exact-fp32 rescue), with ALL
// high-contention global atomics removed from the hot kernel:
//  - R4 counters showed every pipe idle (MFMA 4.8%, VALU 11.6%, HBM 3.5%) at
//    210 us vs ~25 us of real work -> diagnosis: drain of 131K hist atomics
//    (16-line hotspot) + 4096 same-address fp64 sse atomics backpressuring the
//    vmem queue.
//  - SSE: per-block non-atomic partial (ssepart[block], double).
//  - Histogram: rebuilt from out_idx by a 64-block kernel (LDS atomics ->
//    non-atomic histpart), reduced with loss/perplexity in a 1-block finale.
// K-loop / staging / rescue / phase-2 are unchanged from R4 (clean A/B).

#define B_ 32
#define C_ 64
#define HW_ 4096
#define K_ 512
#define N_ (B_ * HW_)
#define NC_ ((long long)N_ * C_)
#define ROWS_ 128
#define NBLK_ (N_ / ROWS_)     // 1024
#define HBLK_ 64               // histogram blocks

typedef __attribute__((ext_vector_type(8))) short short8;
typedef __attribute__((ext_vector_type(4))) float float4_t;

// ---- workspace layout (bytes) ----
// 56      float  snmax               4*max_k ||e_k||^2
// 2112    float  en[512]             ||e_k||^2
// 4160    float  embT32[512*64]      exact fp32 emb, [code][c]
// 135232  ushort fBhi[512*64]        bf16 hi of (-2e), fragment-linear
// 200768  ushort fBlo[512*64]        bf16 lo of (-2e), fragment-linear
// 266304  double ssepart[1024]
// 274496  int    histpart[64*512]
// total   405568

__device__ __forceinline__ unsigned short f2bf(float f) {
    unsigned u = __float_as_uint(f);
    u += 0x7fffu + ((u >> 16) & 1u);   // RNE
    return (unsigned short)(u >> 16);
}
__device__ __forceinline__ float bf2f(unsigned short h) {
    return __uint_as_float(((unsigned)h) << 16);
}
// LDS A-tile (bf16 frag) offset: [row-tile][k-group][row-in-tile][8 k]
__device__ __forceinline__ int offA(int r, int c) {
    return ((r >> 4) << 10) + ((c >> 3) << 7) + ((r & 15) << 3) + (c & 7);
}
__device__ __forceinline__ void merge2(float& m1, int& i1, float& m2,
                                       float om1, int oi1, float om2) {
    if (om1 < m1) { m2 = fminf(m1, om2); m1 = om1; i1 = oi1; }
    else          { m2 = fminf(m2, om1); }
}

// ---------------- prologue ----------------
__global__ __launch_bounds__(512) void vq_init(const float* __restrict__ emb,
                                               float* __restrict__ snmax_p,
                                               float* __restrict__ en,
                                               float* __restrict__ embT32,
                                               unsigned short* __restrict__ fBhi,
                                               unsigned short* __restrict__ fBlo) {
    __shared__ float smax[8];
    int k = threadIdx.x;                  // code 0..511
    if (blockIdx.x < 64) {
        int c = blockIdx.x;
        float e = emb[c * K_ + k];        // coalesced over k
        embT32[k * C_ + c] = e;
        float s = -2.0f * e;
        unsigned short hi = f2bf(s);
        unsigned short lo = f2bf(s - bf2f(hi));
        // fragment-linear: frag-block fb = [k>>5][(k>>4)&1][c>>5], lane, 8 k
        int kk   = c >> 5;
        int lane = (((c & 31) >> 3) << 4) + (k & 15);
        int fb   = ((k >> 5) << 2) + (((k >> 4) & 1) << 1) + kk;
        int off  = (fb << 9) + (lane << 3) + (c & 7);
        fBhi[off] = hi;
        fBlo[off] = lo;
    } else {
        float s = 0.f;
#pragma unroll
        for (int c = 0; c < C_; ++c) {
            float e = emb[c * K_ + k];
            s += e * e;
        }
        en[k] = s;
        float m = s;
#pragma unroll
        for (int off = 32; off > 0; off >>= 1)
            m = fmaxf(m, __shfl_down(m, off, 64));
        if ((k & 63) == 0) smax[k >> 6] = m;
        __syncthreads();
        if (k == 0) {
            float mm = smax[0];
#pragma unroll
            for (int w2 = 1; w2 < 8; ++w2) mm = fmaxf(mm, smax[w2]);
            *snmax_p = 4.0f * mm;
        }
    }
}

// ---------------- main kernel ----------------
__global__ __launch_bounds__(256, 3) void vq_main(const float* __restrict__ x,
                                                  const float* __restrict__ en_g,
                                                  const float* __restrict__ embT32,
                                                  const unsigned short* __restrict__ fBhi,
                                                  const unsigned short* __restrict__ fBlo,
                                                  const float* __restrict__ snmax_p,
                                                  float* __restrict__ out_q,
                                                  float* __restrict__ out_idx,
                                                  double* __restrict__ ssepart) {
    __shared__ unsigned short Ahi[ROWS_ * C_];   // 16 KB, frag order
    __shared__ unsigned short Alo[ROWS_ * C_];   // 16 KB
    __shared__ float znp[2 * ROWS_];
    __shared__ float sEn[K_];
    __shared__ int   biarr[ROWS_];
    __shared__ int   flaglist[ROWS_];
    __shared__ float wsse[4];
    __shared__ int   nflag;

    const int t   = threadIdx.x;
    const int n0  = blockIdx.x * ROWS_;
    const int b   = n0 >> 12;
    const int hw0 = n0 & 4095;
    const float* xbase = x + ((size_t)b << 18) + hw0;

    if (t == 0) nflag = 0;
    sEn[t]       = en_g[t];
    sEn[256 + t] = en_g[256 + t];

    // ---- stage z: bf16 hi/lo (frag order) + zn partials ----
    float znacc = 0.f;
#pragma unroll 8
    for (int i = 0; i < 32; ++i) {
        int id = (i << 8) + t;
        int c = id >> 7;
        int r = id & 127;
        float v = xbase[((size_t)c << 12) + r];   // 256B coalesced
        znacc += v * v;
        unsigned short hi = f2bf(v);
        unsigned short lo = f2bf(v - bf2f(hi));
        int o = offA(r, c);
        Ahi[o] = hi;
        Alo[o] = lo;
    }
    znp[((t >> 7) << 7) + (t & 127)] = znacc;
    __syncthreads();

    const int lane = t & 63;
    const int w    = t >> 6;             // wave owns row-tiles {2w, 2w+1}
    const int ln15 = lane & 15;
    const int quad = lane >> 4;
    const float snm = *snmax_p;

    // ---- A-frags resident (32 VGPRs) ----
    short8 ah[2][2], al[2][2];
#pragma unroll
    for (int rtl = 0; rtl < 2; ++rtl) {
        int ab = (((2 * w) + rtl) << 10) + (quad << 7) + (ln15 << 3);
        ah[rtl][0] = *(const short8*)(Ahi + ab);
        ah[rtl][1] = *(const short8*)(Ahi + ab + 512);
        al[rtl][0] = *(const short8*)(Alo + ab);
        al[rtl][1] = *(const short8*)(Alo + ab + 512);
    }

    // ---- stream all 512 codes: 16 passes x 2 col-tiles; per-row top-2 ----
    float m1[2][4], m2[2][4];
    int   i1[2][4];
#pragma unroll
    for (int rtl = 0; rtl < 2; ++rtl)
#pragma unroll
        for (int reg = 0; reg < 4; ++reg) {
            m1[rtl][reg] = 3.4e38f; m2[rtl][reg] = 3.4e38f; i1[rtl][reg] = 0;
        }

    for (int p = 0; p < 16; ++p) {
#pragma unroll
        for (int ct = 0; ct < 2; ++ct) {
            const unsigned short* fh = fBhi + ((((p << 2) + (ct << 1)) << 9) + (lane << 3));
            const unsigned short* fl = fBlo + ((((p << 2) + (ct << 1)) << 9) + (lane << 3));
            short8 bh0 = *(const short8*)(fh);          // 1 KB contiguous per instr
            short8 bh1 = *(const short8*)(fh + 512);
            short8 bl0 = *(const short8*)(fl);
            short8 bl1 = *(const short8*)(fl + 512);
            float env = sEn[(p << 5) + (ct << 4) + ln15];
            int   idx = (p << 5) + (ct << 4) + ln15;
#pragma unroll
            for (int rtl = 0; rtl < 2; ++rtl) {
                float4_t a = {0.f, 0.f, 0.f, 0.f};
                a = __builtin_amdgcn_mfma_f32_16x16x32_bf16(ah[rtl][0], bh0, a, 0, 0, 0);
                a = __builtin_amdgcn_mfma_f32_16x16x32_bf16(ah[rtl][1], bh1, a, 0, 0, 0);
                a = __builtin_amdgcn_mfma_f32_16x16x32_bf16(ah[rtl][0], bl0, a, 0, 0, 0);
                a = __builtin_amdgcn_mfma_f32_16x16x32_bf16(ah[rtl][1], bl1, a, 0, 0, 0);
                a = __builtin_amdgcn_mfma_f32_16x16x32_bf16(al[rtl][0], bh0, a, 0, 0, 0);
                a = __builtin_amdgcn_mfma_f32_16x16x32_bf16(al[rtl][1], bh1, a, 0, 0, 0);
#pragma unroll
                for (int reg = 0; reg < 4; ++reg) {
                    float v = a[reg] + env;
                    if (v < m1[rtl][reg]) {
                        m2[rtl][reg] = m1[rtl][reg]; m1[rtl][reg] = v; i1[rtl][reg] = idx;
                    } else {
                        m2[rtl][reg] = fminf(m2[rtl][reg], v);
                    }
                }
            }
        }
    }

    // ---- 16-lane butterfly finalize + flag decision ----
#pragma unroll
    for (int rtl = 0; rtl < 2; ++rtl)
#pragma unroll
        for (int reg = 0; reg < 4; ++reg) {
            float a1 = m1[rtl][reg], a2 = m2[rtl][reg];
            int   ai = i1[rtl][reg];
#pragma unroll
            for (int s = 1; s < 16; s <<= 1) {
                float o1 = __shfl_xor(a1, s, 16);
                int   oi = __shfl_xor(ai, s, 16);
                float o2 = __shfl_xor(a2, s, 16);
                merge2(a1, ai, a2, o1, oi, o2);
            }
            if (ln15 == 0) {
                int row = (((2 * w) + rtl) << 4) + (quad << 2) + reg;
                float znr = znp[row] + znp[128 + row];
                float W = 1.4e-4f * __builtin_sqrtf(znr * snm) + 1e-3f;  // sound 2x err bound
                biarr[row] = ai;
                if (a2 > a1 + W) {          // gap > W => approx argmin == exact argmin
                    out_idx[n0 + row] = (float)ai;
                } else {
                    int pos = atomicAdd(&nflag, 1);   // LDS atomic
                    flaglist[pos] = row;
                }
            }
        }
    __syncthreads();

    // ---- exact fp32 rescue (one wave per flagged row; ~1% of rows) ----
    int nf = nflag;
    for (int f = w; f < nf; f += 4) {
        int r = flaglist[f];
        float zl = xbase[((size_t)lane << 12) + r];   // exact z[lane], L2-hot
        float d[8];
#pragma unroll
        for (int j = 0; j < 8; ++j) d[j] = 0.f;
        for (int c4 = 0; c4 < 16; ++c4) {
            float z0 = __shfl(zl, (c4 << 2) + 0, 64);
            float z1 = __shfl(zl, (c4 << 2) + 1, 64);
            float z2 = __shfl(zl, (c4 << 2) + 2, 64);
            float z3 = __shfl(zl, (c4 << 2) + 3, 64);
#pragma unroll
            for (int j = 0; j < 8; ++j) {
                float4 e = *(const float4*)(embT32 + ((((lane << 3) + j) << 6) + (c4 << 2)));
                d[j] = fmaf(z0, e.x, d[j]);
                d[j] = fmaf(z1, e.y, d[j]);
                d[j] = fmaf(z2, e.z, d[j]);
                d[j] = fmaf(z3, e.w, d[j]);
            }
        }
        float znr = znp[r] + znp[128 + r];
        float best = 3.4e38f;
        int   bidx = 0;
#pragma unroll
        for (int j = 0; j < 8; ++j) {
            int k = (lane << 3) + j;
            float dist = (znr + sEn[k]) - 2.f * d[j];   // reference eval order
            if (dist < best) { best = dist; bidx = k; }
        }
#pragma unroll
        for (int off = 32; off > 0; off >>= 1) {
            float ov = __shfl_down(best, off, 64);
            int   oi = __shfl_down(bidx, off, 64);
            if (ov < best || (ov == best && oi < bidx)) { best = ov; bidx = oi; }
        }
        if (lane == 0) {
            biarr[r] = bidx;
            out_idx[n0 + r] = (float)bidx;
        }
    }
    __syncthreads();

    // ---- phase 2: float4 gather of chosen codes, coalesced q store, SSE ----
    float sacc = 0.f;
#pragma unroll
    for (int i = 0; i < 2; ++i) {
        int id2 = (i << 8) + t;
        int r  = id2 & 127;
        int p2 = id2 >> 7;
        int code = biarr[r];
        const float* ebase = embT32 + ((code << 6) + (p2 << 4));
        float* qb = out_q + ((size_t)b << 18) + hw0 + r;
#pragma unroll
        for (int j = 0; j < 4; ++j) {
            float4 q4 = *(const float4*)(ebase + (j << 2));
            int c = (p2 << 4) + (j << 2);
            int o = offA(r, c);
            ushort4 h4 = *(const ushort4*)(Ahi + o);
            ushort4 l4 = *(const ushort4*)(Alo + o);
            float z0 = bf2f(h4.x) + bf2f(l4.x);
            float z1 = bf2f(h4.y) + bf2f(l4.y);
            float z2 = bf2f(h4.z) + bf2f(l4.z);
            float z3 = bf2f(h4.w) + bf2f(l4.w);
            float d0 = q4.x - z0, d1 = q4.y - z1, d2 = q4.z - z2, d3 = q4.w - z3;
            sacc += d0 * d0 + d1 * d1 + d2 * d2 + d3 * d3;
            qb[(size_t)(c + 0) << 12] = q4.x;
            qb[(size_t)(c + 1) << 12] = q4.y;
            qb[(size_t)(c + 2) << 12] = q4.z;
            qb[(size_t)(c + 3) << 12] = q4.w;
        }
    }
#pragma unroll
    for (int off = 32; off > 0; off >>= 1)
        sacc += __shfl_down(sacc, off, 64);
    if (lane == 0) wsse[w] = sacc;
    __syncthreads();
    if (t == 0)
        ssepart[blockIdx.x] = (double)wsse[0] + (double)wsse[1]
                            + (double)wsse[2] + (double)wsse[3];
}

// ---------------- histogram from out_idx (64 blocks) ----------------
__global__ __launch_bounds__(256) void vq_hist(const float* __restrict__ out_idx,
                                               int* __restrict__ histpart) {
    __shared__ int h[K_];
    int t = threadIdx.x;
    h[t] = 0; h[t + 256] = 0;
    __syncthreads();
    const float* ip = out_idx + blockIdx.x * (N_ / HBLK_);
#pragma unroll
    for (int i = 0; i < (N_ / HBLK_) / 256; ++i) {
        int k = (int)ip[(i << 8) + t];
        atomicAdd(&h[k], 1);              // LDS atomic
    }
    __syncthreads();
    histpart[blockIdx.x * K_ + t]       = h[t];
    histpart[blockIdx.x * K_ + 256 + t] = h[t + 256];
}

// ---------------- finale: loss + perplexity (1 block) ----------------
__global__ __launch_bounds__(512) void vq_final(const int* __restrict__ histpart,
                                                const double* __restrict__ ssepart,
                                                float* __restrict__ out_loss,
                                                float* __restrict__ out_perp) {
    __shared__ float  wsf[8];
    __shared__ double wsd[8];
    int t = threadIdx.x;
    int hsum = 0;
#pragma unroll 8
    for (int b = 0; b < HBLK_; ++b)
        hsum += histpart[b * K_ + t];     // coalesced over t
    float p = (float)hsum / (float)N_;
    float s = p * logf(p + 1e-10f);
    double d = ssepart[t] + ssepart[t + 512];
#pragma unroll
    for (int off = 32; off > 0; off >>= 1) {
        s += __shfl_down(s, off, 64);
        d += __shfl_down(d, off, 64);
    }
    if ((t & 63) == 0) { wsf[t >> 6] = s; wsd[t >> 6] = d; }
    __syncthreads();
    if (t == 0) {
        float  S = 0.f;
        double D = 0.0;
#pragma unroll
        for (int w = 0; w < 8; ++w) { S += wsf[w]; D += wsd[w]; }
        *out_perp = expf(-S);
        *out_loss = (float)(1.25 * D / (double)NC_);
    }
}

extern "C" void kernel_launch(void* const* d_in, const int* in_sizes, int n_in,
                              void* d_out, int out_size, void* d_ws, size_t ws_size,
                              hipStream_t stream) {
    const float* x   = (const float*)d_in[0];
    const float* emb = (const float*)d_in[1];

    float* out      = (float*)d_out;
    float* out_loss = out;
    float* out_q    = out + 1;
    float* out_perp = out + 1 + (size_t)N_ * C_;
    float* out_idx  = out + 2 + (size_t)N_ * C_;

    char* ws = (char*)d_ws;
    float*          snmax_p  = (float*)(ws + 56);
    float*          en       = (float*)(ws + 2112);
    float*          embT32   = (float*)(ws + 4160);
    unsigned short* fBhi     = (unsigned short*)(ws + 135232);
    unsigned short* fBlo     = (unsigned short*)(ws + 200768);
    double*         ssepart  = (double*)(ws + 266304);
    int*            histpart = (int*)(ws + 274496);

    vq_init<<<65, 512, 0, stream>>>(emb, snmax_p, en, embT32, fBhi, fBlo);
    vq_main<<<NBLK_, 256, 0, stream>>>(x, en, embT32, fBhi, fBlo, snmax_p,
                                       out_q, out_idx, ssepart);
    vq_hist<<<HBLK_, 256, 0, stream>>>(out_idx, histpart);
    vq_final<<<1, 512, 0, stream>>>(histpart, ssepart, out_loss, out_perp);
}

// Round 6
// 154.644 us; speedup vs baseline: 2.4328x; 1.0426x over previous
//
#include <hip/hip_runtime.h>

// VQ-VAE vector quantizer — R6.
// R5 post-mortem: latency-bound (VALU 26%, MFMA 11%, HBM 7%, occ 17%≈1.4 blk/CU).
// R6: occupancy + ILP restructure.
//  - ROWS_=64/block (2048 blocks): 1 row-tile per wave -> K-loop VGPR ~80,
//    LDS ~12 KB (single A-stage buffer reused hi->lo, x kept in 16 regs).
//  - MFMA accumulator split into 2 independent 3-chains (k-chunk 0/1).
//  - phase 2 (q gather/store + SSE) fused, computed from A-fragment registers
//    (no fp32 LDS tile, no separate apply kernel).
//  - histogram partials reuse the dead fB workspace region.

#define B_ 32
#define C_ 64
#define HW_ 4096
#define K_ 512
#define N_ (B_ * HW_)
#define NC_ ((long long)N_ * C_)
#define ROWS_ 64
#define NBLK_ (N_ / ROWS_)     // 2048
#define HBLK_ 64

typedef __attribute__((ext_vector_type(8))) short short8;
typedef __attribute__((ext_vector_type(4))) float float4_t;

// ---- workspace layout (bytes) ----
// 56      float  snmax               4*max_k ||e_k||^2
// 2112    float  en[512]
// 4160    float  embT32[512*64]      exact fp32 emb, [code][c]
// 135232  ushort fBhi[512*64]        bf16 hi of (-2e), fragment-linear
// 200768  ushort fBlo[512*64]        bf16 lo of (-2e), fragment-linear
// 135232  int    histpart[64*512]    (reuses fB region AFTER vq_argmin)
// 266304  double ssepart[2048]       (16 KB) -> end 282688

__device__ __forceinline__ unsigned short f2bf(float f) {
    unsigned u = __float_as_uint(f);
    u += 0x7fffu + ((u >> 16) & 1u);   // RNE
    return (unsigned short)(u >> 16);
}
__device__ __forceinline__ float bf2f(unsigned short h) {
    return __uint_as_float(((unsigned)h) << 16);
}
// LDS A-tile (bf16 frag) offset: [row-tile][k-group][row-in-tile][8 k]
__device__ __forceinline__ int offA(int r, int c) {
    return ((r >> 4) << 10) + ((c >> 3) << 7) + ((r & 15) << 3) + (c & 7);
}
__device__ __forceinline__ void merge2(float& m1, int& i1, float& m2,
                                       float om1, int oi1, float om2) {
    if (om1 < m1) { m2 = fminf(m1, om2); m1 = om1; i1 = oi1; }
    else          { m2 = fminf(m2, om1); }
}

// ---------------- prologue ----------------
__global__ __launch_bounds__(512) void vq_init(const float* __restrict__ emb,
                                               float* __restrict__ snmax_p,
                                               float* __restrict__ en,
                                               float* __restrict__ embT32,
                                               unsigned short* __restrict__ fBhi,
                                               unsigned short* __restrict__ fBlo) {
    __shared__ float smax[8];
    int k = threadIdx.x;                  // code 0..511
    if (blockIdx.x < 64) {
        int c = blockIdx.x;
        float e = emb[c * K_ + k];        // coalesced over k
        embT32[k * C_ + c] = e;
        float s = -2.0f * e;
        unsigned short hi = f2bf(s);
        unsigned short lo = f2bf(s - bf2f(hi));
        // fragment-linear: fb = [k>>5][(k>>4)&1][c>>5], then lane, then 8 k
        int kk   = c >> 5;
        int lane = (((c & 31) >> 3) << 4) + (k & 15);
        int fb   = ((k >> 5) << 2) + (((k >> 4) & 1) << 1) + kk;
        int off  = (fb << 9) + (lane << 3) + (c & 7);
        fBhi[off] = hi;
        fBlo[off] = lo;
    } else {
        float s = 0.f;
#pragma unroll
        for (int c = 0; c < C_; ++c) {
            float e = emb[c * K_ + k];
            s += e * e;
        }
        en[k] = s;
        float m = s;
#pragma unroll
        for (int off = 32; off > 0; off >>= 1)
            m = fmaxf(m, __shfl_down(m, off, 64));
        if ((k & 63) == 0) smax[k >> 6] = m;
        __syncthreads();
        if (k == 0) {
            float mm = smax[0];
#pragma unroll
            for (int w2 = 1; w2 < 8; ++w2) mm = fmaxf(mm, smax[w2]);
            *snmax_p = 4.0f * mm;
        }
    }
}

// ---------------- main kernel: argmin + q + SSE ----------------
__global__ __launch_bounds__(256) void vq_argmin(const float* __restrict__ x,
                                                 const float* __restrict__ en_g,
                                                 const float* __restrict__ embT32,
                                                 const unsigned short* __restrict__ fBhi,
                                                 const unsigned short* __restrict__ fBlo,
                                                 const float* __restrict__ snmax_p,
                                                 float* __restrict__ out_q,
                                                 float* __restrict__ out_idx,
                                                 double* __restrict__ ssepart) {
    __shared__ unsigned short Ast[ROWS_ * C_];   // 8 KB, reused hi -> lo
    __shared__ float sEn[K_];                    // 2 KB
    __shared__ float znp[4 * ROWS_];             // 1 KB
    __shared__ int   biarr[ROWS_];
    __shared__ int   flaglist[ROWS_];
    __shared__ float wsse[4];
    __shared__ int   nflag;

    const int t   = threadIdx.x;
    const int n0  = blockIdx.x * ROWS_;
    const int b   = n0 >> 12;
    const int hw0 = n0 & 4095;
    const float* xbase = x + ((size_t)b << 18) + hw0;

    if (t == 0) nflag = 0;
    sEn[t]       = en_g[t];
    sEn[256 + t] = en_g[256 + t];

    // ---- stage hi (x retained in regs); thread owns row r=t&63, c = 4i + (t>>6) ----
    float v[16];
    float znacc = 0.f;
#pragma unroll
    for (int i = 0; i < 16; ++i) {
        int id = (i << 8) + t;
        int c = id >> 6;
        int r = id & 63;
        float val = xbase[((size_t)c << 12) + r];   // 256B coalesced
        v[i] = val;
        znacc += val * val;
        Ast[offA(r, c)] = f2bf(val);
    }
    znp[((t >> 6) << 6) + (t & 63)] = znacc;
    __syncthreads();

    const int lane = t & 63;
    const int w    = t >> 6;             // wave owns row-tile w
    const int ln15 = lane & 15;
    const int quad = lane >> 4;
    const float snm = *snmax_p;

    // ---- A-hi frags (16 VGPRs) ----
    const int ab = (w << 10) + (quad << 7) + (ln15 << 3);
    short8 ah0 = *(const short8*)(Ast + ab);
    short8 ah1 = *(const short8*)(Ast + ab + 512);
    __syncthreads();

    // ---- stage lo into same buffer ----
#pragma unroll
    for (int i = 0; i < 16; ++i) {
        int id = (i << 8) + t;
        int c = id >> 6;
        int r = id & 63;
        float val = v[i];
        unsigned short hi = f2bf(val);
        Ast[offA(r, c)] = f2bf(val - bf2f(hi));
    }
    __syncthreads();
    short8 al0 = *(const short8*)(Ast + ab);
    short8 al1 = *(const short8*)(Ast + ab + 512);

    // ---- stream 512 codes: 16 passes x 2 col-tiles; per-row top-2 ----
    float m1[4], m2[4];
    int   i1[4];
#pragma unroll
    for (int reg = 0; reg < 4; ++reg) {
        m1[reg] = 3.4e38f; m2[reg] = 3.4e38f; i1[reg] = 0;
    }

    for (int p = 0; p < 16; ++p) {
#pragma unroll
        for (int ct = 0; ct < 2; ++ct) {
            const int fbase = ((((p << 2) + (ct << 1)) << 9) + (lane << 3));
            short8 bh0 = *(const short8*)(fBhi + fbase);        // 1 KB/instr, L1/L2-hot
            short8 bh1 = *(const short8*)(fBhi + fbase + 512);
            short8 bl0 = *(const short8*)(fBlo + fbase);
            short8 bl1 = *(const short8*)(fBlo + fbase + 512);
            float env = sEn[(p << 5) + (ct << 4) + ln15];
            int   idx = (p << 5) + (ct << 4) + ln15;
            // two independent 3-MFMA chains (k-chunk 0 / 1)
            float4_t a0 = {0.f, 0.f, 0.f, 0.f};
            float4_t a1 = {0.f, 0.f, 0.f, 0.f};
            a0 = __builtin_amdgcn_mfma_f32_16x16x32_bf16(al0, bh0, a0, 0, 0, 0);
            a1 = __builtin_amdgcn_mfma_f32_16x16x32_bf16(al1, bh1, a1, 0, 0, 0);
            a0 = __builtin_amdgcn_mfma_f32_16x16x32_bf16(ah0, bl0, a0, 0, 0, 0);
            a1 = __builtin_amdgcn_mfma_f32_16x16x32_bf16(ah1, bl1, a1, 0, 0, 0);
            a0 = __builtin_amdgcn_mfma_f32_16x16x32_bf16(ah0, bh0, a0, 0, 0, 0);
            a1 = __builtin_amdgcn_mfma_f32_16x16x32_bf16(ah1, bh1, a1, 0, 0, 0);
#pragma unroll
            for (int reg = 0; reg < 4; ++reg) {
                float vv = (a0[reg] + a1[reg]) + env;
                if (vv < m1[reg]) {
                    m2[reg] = m1[reg]; m1[reg] = vv; i1[reg] = idx;
                } else {
                    m2[reg] = fminf(m2[reg], vv);
                }
            }
        }
    }

    // ---- 16-lane butterfly finalize + flag decision ----
#pragma unroll
    for (int reg = 0; reg < 4; ++reg) {
        float a1v = m1[reg], a2v = m2[reg];
        int   ai  = i1[reg];
#pragma unroll
        for (int s = 1; s < 16; s <<= 1) {
            float o1 = __shfl_xor(a1v, s, 16);
            int   oi = __shfl_xor(ai, s, 16);
            float o2 = __shfl_xor(a2v, s, 16);
            merge2(a1v, ai, a2v, o1, oi, o2);
        }
        if (ln15 == 0) {
            int row = (w << 4) + (quad << 2) + reg;
            float znr = znp[row] + znp[64 + row] + znp[128 + row] + znp[192 + row];
            float W = 1.4e-4f * __builtin_sqrtf(znr * snm) + 1e-3f;  // sound 2x err bound
            biarr[row] = ai;
            if (a2v > a1v + W) {          // gap > W => approx argmin == exact argmin
                out_idx[n0 + row] = (float)ai;
            } else {
                int pos = atomicAdd(&nflag, 1);   // LDS atomic
                flaglist[pos] = row;
            }
        }
    }
    __syncthreads();

    // ---- exact fp32 rescue (one wave per flagged row; ~1% of rows) ----
    int nf = nflag;
    for (int f = w; f < nf; f += 4) {
        int r = flaglist[f];
        float zl = xbase[((size_t)lane << 12) + r];   // exact z[lane], L2-hot
        float d[8];
#pragma unroll
        for (int j = 0; j < 8; ++j) d[j] = 0.f;
        for (int c4 = 0; c4 < 16; ++c4) {
            float z0 = __shfl(zl, (c4 << 2) + 0, 64);
            float z1 = __shfl(zl, (c4 << 2) + 1, 64);
            float z2 = __shfl(zl, (c4 << 2) + 2, 64);
            float z3 = __shfl(zl, (c4 << 2) + 3, 64);
#pragma unroll
            for (int j = 0; j < 8; ++j) {
                float4_t e = *(const float4_t*)(embT32 + ((((lane << 3) + j) << 6) + (c4 << 2)));
                d[j] = fmaf(z0, e[0], d[j]);
                d[j] = fmaf(z1, e[1], d[j]);
                d[j] = fmaf(z2, e[2], d[j]);
                d[j] = fmaf(z3, e[3], d[j]);
            }
        }
        float znr = znp[r] + znp[64 + r] + znp[128 + r] + znp[192 + r];
        float best = 3.4e38f;
        int   bidx = 0;
#pragma unroll
        for (int j = 0; j < 8; ++j) {
            int k = (lane << 3) + j;
            float dist = (znr + sEn[k]) - 2.f * d[j];   // reference eval order
            if (dist < best) { best = dist; bidx = k; }
        }
#pragma unroll
        for (int off = 32; off > 0; off >>= 1) {
            float ov = __shfl_down(best, off, 64);
            int   oi = __shfl_down(bidx, off, 64);
            if (ov < best || (ov == best && oi < bidx)) { best = ov; bidx = oi; }
        }
        if (lane == 0) {
            biarr[r] = bidx;
            out_idx[n0 + r] = (float)bidx;
        }
    }
    __syncthreads();

    // ---- phase 2 (register-based): lane covers row = w*16+ln15, c = quad*8+j (+32) ----
    const int myrow = (w << 4) + ln15;
    const int code  = biarr[myrow];
    const float* eb = embT32 + (code << 6) + (quad << 3);
    float4_t e0 = *(const float4_t*)(eb);          // c = quad*8 + 0..3
    float4_t e1 = *(const float4_t*)(eb + 4);      // c = quad*8 + 4..7
    float4_t e2 = *(const float4_t*)(eb + 32);     // c = 32 + quad*8 + 0..3
    float4_t e3 = *(const float4_t*)(eb + 36);     // c = 32 + quad*8 + 4..7
    float* qrow = out_q + ((size_t)b << 18) + hw0 + myrow;
    float sacc = 0.f;
#pragma unroll
    for (int j = 0; j < 4; ++j) {
        int c0 = (quad << 3) + j;
        int c1 = (quad << 3) + 4 + j;
        // chunk 0 (c < 32): frags ah0/al0
        float zA = bf2f((unsigned short)ah0[j])     + bf2f((unsigned short)al0[j]);
        float zB = bf2f((unsigned short)ah0[4 + j]) + bf2f((unsigned short)al0[4 + j]);
        float dA = e0[j] - zA, dB = e1[j] - zB;
        sacc += dA * dA + dB * dB;
        qrow[(size_t)c0 << 12] = e0[j];
        qrow[(size_t)c1 << 12] = e1[j];
        // chunk 1 (c >= 32): frags ah1/al1
        float zC = bf2f((unsigned short)ah1[j])     + bf2f((unsigned short)al1[j]);
        float zD = bf2f((unsigned short)ah1[4 + j]) + bf2f((unsigned short)al1[4 + j]);
        float dC = e2[j] - zC, dD = e3[j] - zD;
        sacc += dC * dC + dD * dD;
        qrow[(size_t)(32 + c0) << 12] = e2[j];
        qrow[(size_t)(32 + c1) << 12] = e3[j];
    }
#pragma unroll
    for (int off = 32; off > 0; off >>= 1)
        sacc += __shfl_down(sacc, off, 64);
    if (lane == 0) wsse[w] = sacc;
    __syncthreads();
    if (t == 0)
        ssepart[blockIdx.x] = (double)wsse[0] + (double)wsse[1]
                            + (double)wsse[2] + (double)wsse[3];
}

// ---------------- histogram from out_idx (64 blocks) ----------------
__global__ __launch_bounds__(256) void vq_hist(const float* __restrict__ out_idx,
                                               int* __restrict__ histpart) {
    __shared__ int h[K_];
    int t = threadIdx.x;
    h[t] = 0; h[t + 256] = 0;
    __syncthreads();
    const float* ip = out_idx + blockIdx.x * (N_ / HBLK_);
#pragma unroll
    for (int i = 0; i < (N_ / HBLK_) / 256; ++i) {
        int k = (int)ip[(i << 8) + t];
        atomicAdd(&h[k], 1);              // LDS atomic
    }
    __syncthreads();
    histpart[blockIdx.x * K_ + t]       = h[t];
    histpart[blockIdx.x * K_ + 256 + t] = h[t + 256];
}

// ---------------- finale: loss + perplexity (1 block) ----------------
__global__ __launch_bounds__(512) void vq_final(const int* __restrict__ histpart,
                                                const double* __restrict__ ssepart,
                                                float* __restrict__ out_loss,
                                                float* __restrict__ out_perp) {
    __shared__ float  wsf[8];
    __shared__ double wsd[8];
    int t = threadIdx.x;
    int hsum = 0;
#pragma unroll 8
    for (int b = 0; b < HBLK_; ++b)
        hsum += histpart[b * K_ + t];     // coalesced over t
    float p = (float)hsum / (float)N_;
    float s = p * logf(p + 1e-10f);
    double d = ssepart[t] + ssepart[t + 512] + ssepart[t + 1024] + ssepart[t + 1536];
#pragma unroll
    for (int off = 32; off > 0; off >>= 1) {
        s += __shfl_down(s, off, 64);
        d += __shfl_down(d, off, 64);
    }
    if ((t & 63) == 0) { wsf[t >> 6] = s; wsd[t >> 6] = d; }
    __syncthreads();
    if (t == 0) {
        float  S = 0.f;
        double D = 0.0;
#pragma unroll
        for (int w = 0; w < 8; ++w) { S += wsf[w]; D += wsd[w]; }
        *out_perp = expf(-S);
        *out_loss = (float)(1.25 * D / (double)NC_);
    }
}

extern "C" void kernel_launch(void* const* d_in, const int* in_sizes, int n_in,
                              void* d_out, int out_size, void* d_ws, size_t ws_size,
                              hipStream_t stream) {
    const float* x   = (const float*)d_in[0];
    const float* emb = (const float*)d_in[1];

    float* out      = (float*)d_out;
    float* out_loss = out;
    float* out_q    = out + 1;
    float* out_perp = out + 1 + (size_t)N_ * C_;
    float* out_idx  = out + 2 + (size_t)N_ * C_;

    char* ws = (char*)d_ws;
    float*          snmax_p  = (float*)(ws + 56);
    float*          en       = (float*)(ws + 2112);
    float*          embT32   = (float*)(ws + 4160);
    unsigned short* fBhi     = (unsigned short*)(ws + 135232);
    unsigned short* fBlo     = (unsigned short*)(ws + 200768);
    int*            histpart = (int*)(ws + 135232);   // reuses fB region (dead after argmin)
    double*         ssepart  = (double*)(ws + 266304);

    vq_init<<<65, 512, 0, stream>>>(emb, snmax_p, en, embT32, fBhi, fBlo);
    vq_argmin<<<NBLK_, 256, 0, stream>>>(x, en, embT32, fBhi, fBlo, snmax_p,
                                         out_q, out_idx, ssepart);
    vq_hist<<<HBLK_, 256, 0, stream>>>(out_idx, histpart);
    vq_final<<<1, 512, 0, stream>>>(histpart, ssepart, out_loss, out_perp);
}